// Round 1
// baseline (700.887 us; speedup 1.0000x reference)
//
#include <hip/hip_runtime.h>

#define N_NODES 100000
#define N_EDGES 1600000
#define IN_F 128
#define H_F 64

// ---------------- degree histogram ----------------
__global__ void degree_kernel(const int* __restrict__ src, const int* __restrict__ dst,
                              int* __restrict__ deg_src, int* __restrict__ deg_dst, int E) {
    int e = blockIdx.x * blockDim.x + threadIdx.x;
    if (e < E) {
        atomicAdd(&deg_src[src[e]], 1);
        atomicAdd(&deg_dst[dst[e]], 1);
    }
}

__global__ void norm_kernel(const int* __restrict__ deg_src, const int* __restrict__ deg_dst,
                            float* __restrict__ out_norm, float* __restrict__ in_norm, int N) {
    int i = blockIdx.x * blockDim.x + threadIdx.x;
    if (i < N) {
        out_norm[i] = rsqrtf((float)max(deg_src[i], 1));
        in_norm[i]  = rsqrtf((float)max(deg_dst[i], 1));
    }
}

// ---------------- exclusive scan (3-phase) ----------------
__global__ void scan_block_kernel(const int* __restrict__ deg, int* __restrict__ out,
                                  int* __restrict__ bsums, int N) {
    __shared__ int temp[256];
    int tid = threadIdx.x;
    int i = blockIdx.x * 256 + tid;
    int v = (i < N) ? deg[i] : 0;
    temp[tid] = v;
    __syncthreads();
    for (int off = 1; off < 256; off <<= 1) {
        int t = (tid >= off) ? temp[tid - off] : 0;
        __syncthreads();
        temp[tid] += t;
        __syncthreads();
    }
    int excl = (tid > 0) ? temp[tid - 1] : 0;
    if (i < N) out[i] = excl;
    if (tid == 255) bsums[blockIdx.x] = temp[255];
}

__global__ void scan_sums_kernel(int* __restrict__ bsums, int B) {
    __shared__ int temp[512];
    int tid = threadIdx.x;
    int v = (tid < B) ? bsums[tid] : 0;
    temp[tid] = v;
    __syncthreads();
    for (int off = 1; off < 512; off <<= 1) {
        int t = (tid >= off) ? temp[tid - off] : 0;
        __syncthreads();
        temp[tid] += t;
        __syncthreads();
    }
    int excl = (tid > 0) ? temp[tid - 1] : 0;
    if (tid < B) bsums[tid] = excl;
}

__global__ void scan_add_kernel(int* __restrict__ row_off, const int* __restrict__ bsums,
                                int* __restrict__ cursor, int N, int E) {
    int i = blockIdx.x * 256 + threadIdx.x;
    if (i < N) {
        int r = row_off[i] + bsums[i >> 8];
        row_off[i] = r;
        cursor[i] = r;
    }
    if (i == 0) row_off[N] = E;
}

// ---------------- CSR scatter ----------------
__global__ void scatter_kernel(const int* __restrict__ src, const int* __restrict__ dst,
                               int* __restrict__ cursor, int* __restrict__ csr_src, int E) {
    int e = blockIdx.x * blockDim.x + threadIdx.x;
    if (e < E) {
        int p = atomicAdd(&cursor[dst[e]], 1);
        csr_src[p] = src[e];
    }
}

// ---------------- row-scaled dense GEMM: out[N,64] = (in * scale) @ W[K,64] ----------------
template <int K>
__global__ __launch_bounds__(256) void gemm_rows_kernel(
        const float* __restrict__ in, const float* __restrict__ W,
        const float* __restrict__ scale, float* __restrict__ out, int N) {
    __shared__ float Wlds[K * 64];
    int tid = threadIdx.x;
    for (int i = tid; i < K * 64; i += blockDim.x) Wlds[i] = W[i];
    __syncthreads();

    int lane = tid & 63;
    int wave = tid >> 6;
    int wpb = blockDim.x >> 6;
    int gw = blockIdx.x * wpb + wave;
    int stride = gridDim.x * wpb;

    for (int row = gw; row < N; row += stride) {
        float r0 = in[(size_t)row * K + lane];
        float r1 = (K > 64) ? in[(size_t)row * K + 64 + lane] : 0.f;
        float acc = 0.f;
#pragma unroll
        for (int k = 0; k < 64; k++) {
            float a = __shfl(r0, k);
            acc = fmaf(a, Wlds[k * 64 + lane], acc);
        }
        if (K > 64) {
#pragma unroll
            for (int k = 0; k < 64; k++) {
                float a = __shfl(r1, k);
                acc = fmaf(a, Wlds[(64 + k) * 64 + lane], acc);
            }
        }
        out[(size_t)row * 64 + lane] = acc * scale[row];
    }
}

// ---------------- CSR aggregation (one wave per node), optional fused 64->2 head ----------------
template <bool FUSE_HEAD>
__global__ __launch_bounds__(256) void agg_kernel(
        const float* __restrict__ X, const int* __restrict__ row_off,
        const int* __restrict__ csr_src, const float* __restrict__ in_norm,
        const float* __restrict__ bias, const float* __restrict__ Wm,
        const float* __restrict__ bm, float* __restrict__ out, int N) {
    int lane = threadIdx.x & 63;
    int wave = threadIdx.x >> 6;
    int v = blockIdx.x * (blockDim.x >> 6) + wave;
    if (v >= N) return;

    int start = row_off[v];
    int end = row_off[v + 1];
    float acc = 0.f;
    for (int base = start; base < end; base += 64) {
        int idx = base + lane;
        int s_e = (idx < end) ? csr_src[idx] : 0;
        int cnt = min(64, end - base);
        for (int t = 0; t < cnt; t++) {
            int s = __shfl(s_e, t);
            acc += X[(size_t)s * 64 + lane];
        }
    }
    float h = fmaf(acc, in_norm[v], bias[lane]);
    h = fmaxf(h, 0.f);

    if (!FUSE_HEAD) {
        out[(size_t)v * 64 + lane] = h;
    } else {
        float p0 = h * Wm[lane * 2 + 0];
        float p1 = h * Wm[lane * 2 + 1];
#pragma unroll
        for (int off = 32; off > 0; off >>= 1) {
            p0 += __shfl_xor(p0, off);
            p1 += __shfl_xor(p1, off);
        }
        if (lane == 0) {
            out[(size_t)v * 2 + 0] = p0 + bm[0];
            out[(size_t)v * 2 + 1] = p1 + bm[1];
        }
    }
}

extern "C" void kernel_launch(void* const* d_in, const int* in_sizes, int n_in,
                              void* d_out, int out_size, void* d_ws, size_t ws_size,
                              hipStream_t stream) {
    const float* feature = (const float*)d_in[0];
    const float* W1 = (const float*)d_in[1];
    const float* b1 = (const float*)d_in[2];
    const float* W2 = (const float*)d_in[3];
    const float* b2 = (const float*)d_in[4];
    const float* Wm = (const float*)d_in[5];
    const float* bm = (const float*)d_in[6];
    const int* src = (const int*)d_in[7];
    const int* dst = (const int*)d_in[8];
    float* out = (float*)d_out;

    const int N = N_NODES, E = N_EDGES;

    char* p = (char*)d_ws;
    int* deg_src = (int*)p;    p += (size_t)N * 4;
    int* deg_dst = (int*)p;    p += (size_t)N * 4;
    float* out_norm = (float*)p; p += (size_t)N * 4;
    float* in_norm = (float*)p;  p += (size_t)N * 4;
    int* row_off = (int*)p;    p += (size_t)(N + 1) * 4;
    int* cursor = (int*)p;     p += (size_t)N * 4;
    int* bsums = (int*)p;      p += 512 * 4;
    int* csr_src = (int*)p;    p += (size_t)E * 4;
    float* X = (float*)p;      p += (size_t)N * 64 * 4;
    float* H = (float*)p;      p += (size_t)N * 64 * 4;

    hipMemsetAsync(deg_src, 0, (size_t)N * 4, stream);
    hipMemsetAsync(deg_dst, 0, (size_t)N * 4, stream);

    degree_kernel<<<(E + 255) / 256, 256, 0, stream>>>(src, dst, deg_src, deg_dst, E);
    norm_kernel<<<(N + 255) / 256, 256, 0, stream>>>(deg_src, deg_dst, out_norm, in_norm, N);

    int nScanBlocks = (N + 255) / 256;  // 391
    scan_block_kernel<<<nScanBlocks, 256, 0, stream>>>(deg_dst, row_off, bsums, N);
    scan_sums_kernel<<<1, 512, 0, stream>>>(bsums, nScanBlocks);
    scan_add_kernel<<<nScanBlocks, 256, 0, stream>>>(row_off, bsums, cursor, N, E);

    scatter_kernel<<<(E + 255) / 256, 256, 0, stream>>>(src, dst, cursor, csr_src, E);

    // layer 1
    gemm_rows_kernel<128><<<1024, 256, 0, stream>>>(feature, W1, out_norm, X, N);
    agg_kernel<false><<<(N + 3) / 4, 256, 0, stream>>>(X, row_off, csr_src, in_norm, b1,
                                                       nullptr, nullptr, H, N);
    // layer 2
    gemm_rows_kernel<64><<<1024, 256, 0, stream>>>(H, W2, out_norm, X, N);
    // fused head
    agg_kernel<true><<<(N + 3) / 4, 256, 0, stream>>>(X, row_off, csr_src, in_norm, b2,
                                                      Wm, bm, out, N);
}

// Round 2
// 576.235 us; speedup vs baseline: 1.2163x; 1.2163x over previous
//
#include <hip/hip_runtime.h>

#define N_NODES 100000
#define N_EDGES 1600000
#define IN_F 128
#define H_F 64

// ---------------- degree histogram ----------------
__global__ void degree_kernel(const int* __restrict__ src, const int* __restrict__ dst,
                              int* __restrict__ deg_src, int* __restrict__ deg_dst, int E) {
    int e = blockIdx.x * blockDim.x + threadIdx.x;
    if (e < E) {
        atomicAdd(&deg_src[src[e]], 1);
        atomicAdd(&deg_dst[dst[e]], 1);
    }
}

__global__ void norm_kernel(const int* __restrict__ deg_src, const int* __restrict__ deg_dst,
                            float* __restrict__ out_norm, float* __restrict__ in_norm, int N) {
    int i = blockIdx.x * blockDim.x + threadIdx.x;
    if (i < N) {
        out_norm[i] = rsqrtf((float)max(deg_src[i], 1));
        in_norm[i]  = rsqrtf((float)max(deg_dst[i], 1));
    }
}

// ---------------- exclusive scan (3-phase) ----------------
__global__ void scan_block_kernel(const int* __restrict__ deg, int* __restrict__ out,
                                  int* __restrict__ bsums, int N) {
    __shared__ int temp[256];
    int tid = threadIdx.x;
    int i = blockIdx.x * 256 + tid;
    int v = (i < N) ? deg[i] : 0;
    temp[tid] = v;
    __syncthreads();
    for (int off = 1; off < 256; off <<= 1) {
        int t = (tid >= off) ? temp[tid - off] : 0;
        __syncthreads();
        temp[tid] += t;
        __syncthreads();
    }
    int excl = (tid > 0) ? temp[tid - 1] : 0;
    if (i < N) out[i] = excl;
    if (tid == 255) bsums[blockIdx.x] = temp[255];
}

__global__ void scan_sums_kernel(int* __restrict__ bsums, int B) {
    __shared__ int temp[512];
    int tid = threadIdx.x;
    int v = (tid < B) ? bsums[tid] : 0;
    temp[tid] = v;
    __syncthreads();
    for (int off = 1; off < 512; off <<= 1) {
        int t = (tid >= off) ? temp[tid - off] : 0;
        __syncthreads();
        temp[tid] += t;
        __syncthreads();
    }
    int excl = (tid > 0) ? temp[tid - 1] : 0;
    if (tid < B) bsums[tid] = excl;
}

__global__ void scan_add_kernel(int* __restrict__ row_off, const int* __restrict__ bsums,
                                int* __restrict__ cursor, int N, int E) {
    int i = blockIdx.x * 256 + threadIdx.x;
    if (i < N) {
        int r = row_off[i] + bsums[i >> 8];
        row_off[i] = r;
        cursor[i] = r;
    }
    if (i == 0) row_off[N] = E;
}

// ---------------- CSR scatter ----------------
__global__ void scatter_kernel(const int* __restrict__ src, const int* __restrict__ dst,
                               int* __restrict__ cursor, int* __restrict__ csr_src, int E) {
    int e = blockIdx.x * blockDim.x + threadIdx.x;
    if (e < E) {
        int p = atomicAdd(&cursor[dst[e]], 1);
        csr_src[p] = src[e];
    }
}

// ---------------- thread-per-row GEMM: out[N,64] = scale[r] * (in[r,:] @ W[K,64]) ----------------
// W is read at wave-uniform addresses -> compiler scalarizes to s_load through
// the scalar cache; inner loop is pure v_fmac_f32 (VGPR, SGPR, VGPR).
template <int K>
__global__ __launch_bounds__(256) void gemm_tpr_kernel(
        const float* __restrict__ in, const float* __restrict__ W,
        const float* __restrict__ scale, float* __restrict__ out, int N) {
    int r = blockIdx.x * blockDim.x + threadIdx.x;
    if (r >= N) return;

    float acc[64];
#pragma unroll
    for (int j = 0; j < 64; j++) acc[j] = 0.f;

    const float* row = in + (size_t)r * K;
#pragma unroll
    for (int k = 0; k < K; k += 4) {
        float4 a = *reinterpret_cast<const float4*>(row + k);
        const float* w0 = W + (size_t)k * 64;
#pragma unroll
        for (int j = 0; j < 64; j++) acc[j] = fmaf(a.x, w0[j], acc[j]);
#pragma unroll
        for (int j = 0; j < 64; j++) acc[j] = fmaf(a.y, w0[64 + j], acc[j]);
#pragma unroll
        for (int j = 0; j < 64; j++) acc[j] = fmaf(a.z, w0[128 + j], acc[j]);
#pragma unroll
        for (int j = 0; j < 64; j++) acc[j] = fmaf(a.w, w0[192 + j], acc[j]);
    }

    float s = scale[r];
    float4* o = reinterpret_cast<float4*>(out + (size_t)r * 64);
#pragma unroll
    for (int j = 0; j < 64; j += 4) {
        float4 v;
        v.x = acc[j + 0] * s;
        v.y = acc[j + 1] * s;
        v.z = acc[j + 2] * s;
        v.w = acc[j + 3] * s;
        o[j >> 2] = v;
    }
}

// ---------------- CSR aggregation (one wave per node), optional fused 64->2 head ----------------
template <bool FUSE_HEAD>
__global__ __launch_bounds__(256) void agg_kernel(
        const float* __restrict__ X, const int* __restrict__ row_off,
        const int* __restrict__ csr_src, const float* __restrict__ in_norm,
        const float* __restrict__ bias, const float* __restrict__ Wm,
        const float* __restrict__ bm, float* __restrict__ out, int N) {
    int lane = threadIdx.x & 63;
    int wave = threadIdx.x >> 6;
    int v = blockIdx.x * (blockDim.x >> 6) + wave;
    if (v >= N) return;

    int start = row_off[v];
    int end = row_off[v + 1];
    float acc = 0.f;
    for (int base = start; base < end; base += 64) {
        int idx = base + lane;
        int s_e = (idx < end) ? csr_src[idx] : 0;
        int cnt = min(64, end - base);
        for (int t = 0; t < cnt; t++) {
            int s = __shfl(s_e, t);
            acc += X[(size_t)s * 64 + lane];
        }
    }
    float h = fmaf(acc, in_norm[v], bias[lane]);
    h = fmaxf(h, 0.f);

    if (!FUSE_HEAD) {
        out[(size_t)v * 64 + lane] = h;
    } else {
        float p0 = h * Wm[lane * 2 + 0];
        float p1 = h * Wm[lane * 2 + 1];
#pragma unroll
        for (int off = 32; off > 0; off >>= 1) {
            p0 += __shfl_xor(p0, off);
            p1 += __shfl_xor(p1, off);
        }
        if (lane == 0) {
            out[(size_t)v * 2 + 0] = p0 + bm[0];
            out[(size_t)v * 2 + 1] = p1 + bm[1];
        }
    }
}

extern "C" void kernel_launch(void* const* d_in, const int* in_sizes, int n_in,
                              void* d_out, int out_size, void* d_ws, size_t ws_size,
                              hipStream_t stream) {
    const float* feature = (const float*)d_in[0];
    const float* W1 = (const float*)d_in[1];
    const float* b1 = (const float*)d_in[2];
    const float* W2 = (const float*)d_in[3];
    const float* b2 = (const float*)d_in[4];
    const float* Wm = (const float*)d_in[5];
    const float* bm = (const float*)d_in[6];
    const int* src = (const int*)d_in[7];
    const int* dst = (const int*)d_in[8];
    float* out = (float*)d_out;

    const int N = N_NODES, E = N_EDGES;

    char* p = (char*)d_ws;
    int* deg_src = (int*)p;    p += (size_t)N * 4;
    int* deg_dst = (int*)p;    p += (size_t)N * 4;
    float* out_norm = (float*)p; p += (size_t)N * 4;
    float* in_norm = (float*)p;  p += (size_t)N * 4;
    int* row_off = (int*)p;    p += (size_t)(N + 1) * 4;
    int* cursor = (int*)p;     p += (size_t)N * 4;
    int* bsums = (int*)p;      p += 512 * 4;
    int* csr_src = (int*)p;    p += (size_t)E * 4;
    float* X = (float*)p;      p += (size_t)N * 64 * 4;
    float* H = (float*)p;      p += (size_t)N * 64 * 4;

    hipMemsetAsync(deg_src, 0, (size_t)N * 4, stream);
    hipMemsetAsync(deg_dst, 0, (size_t)N * 4, stream);

    degree_kernel<<<(E + 255) / 256, 256, 0, stream>>>(src, dst, deg_src, deg_dst, E);
    norm_kernel<<<(N + 255) / 256, 256, 0, stream>>>(deg_src, deg_dst, out_norm, in_norm, N);

    int nScanBlocks = (N + 255) / 256;  // 391
    scan_block_kernel<<<nScanBlocks, 256, 0, stream>>>(deg_dst, row_off, bsums, N);
    scan_sums_kernel<<<1, 512, 0, stream>>>(bsums, nScanBlocks);
    scan_add_kernel<<<nScanBlocks, 256, 0, stream>>>(row_off, bsums, cursor, N, E);

    scatter_kernel<<<(E + 255) / 256, 256, 0, stream>>>(src, dst, cursor, csr_src, E);

    // layer 1
    gemm_tpr_kernel<128><<<(N + 255) / 256, 256, 0, stream>>>(feature, W1, out_norm, X, N);
    agg_kernel<false><<<(N + 3) / 4, 256, 0, stream>>>(X, row_off, csr_src, in_norm, b1,
                                                       nullptr, nullptr, H, N);
    // layer 2
    gemm_tpr_kernel<64><<<(N + 255) / 256, 256, 0, stream>>>(H, W2, out_norm, X, N);
    // fused head
    agg_kernel<true><<<(N + 3) / 4, 256, 0, stream>>>(X, row_off, csr_src, in_norm, b2,
                                                      Wm, bm, out, N);
}

// Round 3
// 557.227 us; speedup vs baseline: 1.2578x; 1.0341x over previous
//
#include <hip/hip_runtime.h>

#define N_NODES 100000
#define N_EDGES 1600000
#define IN_F 128
#define H_F 64

// ---------------- degree histogram ----------------
__global__ void degree_kernel(const int* __restrict__ src, const int* __restrict__ dst,
                              int* __restrict__ deg_src, int* __restrict__ deg_dst, int E) {
    int e = blockIdx.x * blockDim.x + threadIdx.x;
    if (e < E) {
        atomicAdd(&deg_src[src[e]], 1);
        atomicAdd(&deg_dst[dst[e]], 1);
    }
}

__global__ void norm_kernel(const int* __restrict__ deg_src, const int* __restrict__ deg_dst,
                            float* __restrict__ out_norm, float* __restrict__ in_norm, int N) {
    int i = blockIdx.x * blockDim.x + threadIdx.x;
    if (i < N) {
        out_norm[i] = rsqrtf((float)max(deg_src[i], 1));
        in_norm[i]  = rsqrtf((float)max(deg_dst[i], 1));
    }
}

// ---------------- exclusive scan (3-phase) ----------------
__global__ void scan_block_kernel(const int* __restrict__ deg, int* __restrict__ out,
                                  int* __restrict__ bsums, int N) {
    __shared__ int temp[256];
    int tid = threadIdx.x;
    int i = blockIdx.x * 256 + tid;
    int v = (i < N) ? deg[i] : 0;
    temp[tid] = v;
    __syncthreads();
    for (int off = 1; off < 256; off <<= 1) {
        int t = (tid >= off) ? temp[tid - off] : 0;
        __syncthreads();
        temp[tid] += t;
        __syncthreads();
    }
    int excl = (tid > 0) ? temp[tid - 1] : 0;
    if (i < N) out[i] = excl;
    if (tid == 255) bsums[blockIdx.x] = temp[255];
}

__global__ void scan_sums_kernel(int* __restrict__ bsums, int B) {
    __shared__ int temp[512];
    int tid = threadIdx.x;
    int v = (tid < B) ? bsums[tid] : 0;
    temp[tid] = v;
    __syncthreads();
    for (int off = 1; off < 512; off <<= 1) {
        int t = (tid >= off) ? temp[tid - off] : 0;
        __syncthreads();
        temp[tid] += t;
        __syncthreads();
    }
    int excl = (tid > 0) ? temp[tid - 1] : 0;
    if (tid < B) bsums[tid] = excl;
}

__global__ void scan_add_kernel(int* __restrict__ row_off, const int* __restrict__ bsums,
                                int* __restrict__ cursor, int N, int E) {
    int i = blockIdx.x * 256 + threadIdx.x;
    if (i < N) {
        int r = row_off[i] + bsums[i >> 8];
        row_off[i] = r;
        cursor[i] = r;
    }
    if (i == 0) row_off[N] = E;
}

// ---------------- CSR scatter (non-temporal csr writes: avoid L2 line bounce) ----------------
__global__ void scatter_kernel(const int* __restrict__ src, const int* __restrict__ dst,
                               int* __restrict__ cursor, int* __restrict__ csr_src, int E) {
    int e = blockIdx.x * blockDim.x + threadIdx.x;
    if (e < E) {
        int p = atomicAdd(&cursor[dst[e]], 1);
        __builtin_nontemporal_store(src[e], &csr_src[p]);
    }
}

// ---------------- thread-per-row GEMM, 32-col half per blockIdx.y ----------------
// out[r, h*32..h*32+31] = scale[r] * (in[r,:] @ W[:, h*32..])
// W loads are wave-uniform -> scalarized (s_load through K$); 32 accumulators
// keep VGPRs ~50 so no scratch spill (round-2 failure mode: 64 acc spilled).
template <int K>
__global__ __launch_bounds__(256, 4) void gemm_tpr_kernel(
        const float* __restrict__ in, const float* __restrict__ W,
        const float* __restrict__ scale, float* __restrict__ out, int N) {
    int r = blockIdx.x * blockDim.x + threadIdx.x;
    if (r >= N) return;
    const int h = blockIdx.y * 32;  // column half offset

    float acc[32];
#pragma unroll
    for (int j = 0; j < 32; j++) acc[j] = 0.f;

    const float* row = in + (size_t)r * K;
#pragma unroll 4
    for (int k = 0; k < K; k += 4) {
        float4 a = *reinterpret_cast<const float4*>(row + k);
        const float* w0 = W + (size_t)k * 64 + h;
#pragma unroll
        for (int j = 0; j < 32; j++) acc[j] = fmaf(a.x, w0[j], acc[j]);
#pragma unroll
        for (int j = 0; j < 32; j++) acc[j] = fmaf(a.y, w0[64 + j], acc[j]);
#pragma unroll
        for (int j = 0; j < 32; j++) acc[j] = fmaf(a.z, w0[128 + j], acc[j]);
#pragma unroll
        for (int j = 0; j < 32; j++) acc[j] = fmaf(a.w, w0[192 + j], acc[j]);
    }

    float s = scale[r];
    float4* o = reinterpret_cast<float4*>(out + (size_t)r * 64 + h);
#pragma unroll
    for (int j = 0; j < 32; j += 4) {
        float4 v;
        v.x = acc[j + 0] * s;
        v.y = acc[j + 1] * s;
        v.z = acc[j + 2] * s;
        v.w = acc[j + 3] * s;
        o[j >> 2] = v;
    }
}

// ---------------- CSR aggregation (one wave per node), optional fused 64->2 head ----------------
template <bool FUSE_HEAD>
__global__ __launch_bounds__(256) void agg_kernel(
        const float* __restrict__ X, const int* __restrict__ row_off,
        const int* __restrict__ csr_src, const float* __restrict__ in_norm,
        const float* __restrict__ bias, const float* __restrict__ Wm,
        const float* __restrict__ bm, float* __restrict__ out, int N) {
    int lane = threadIdx.x & 63;
    int wave = threadIdx.x >> 6;
    int v = blockIdx.x * (blockDim.x >> 6) + wave;
    if (v >= N) return;

    int start = row_off[v];
    int end = row_off[v + 1];
    float acc = 0.f;
    for (int base = start; base < end; base += 64) {
        int idx = base + lane;
        int s_e = (idx < end) ? csr_src[idx] : 0;
        int cnt = min(64, end - base);
        for (int t = 0; t < cnt; t++) {
            int s = __shfl(s_e, t);
            acc += X[(size_t)s * 64 + lane];
        }
    }
    float h = fmaf(acc, in_norm[v], bias[lane]);
    h = fmaxf(h, 0.f);

    if (!FUSE_HEAD) {
        out[(size_t)v * 64 + lane] = h;
    } else {
        float p0 = h * Wm[lane * 2 + 0];
        float p1 = h * Wm[lane * 2 + 1];
#pragma unroll
        for (int off = 32; off > 0; off >>= 1) {
            p0 += __shfl_xor(p0, off);
            p1 += __shfl_xor(p1, off);
        }
        if (lane == 0) {
            out[(size_t)v * 2 + 0] = p0 + bm[0];
            out[(size_t)v * 2 + 1] = p1 + bm[1];
        }
    }
}

extern "C" void kernel_launch(void* const* d_in, const int* in_sizes, int n_in,
                              void* d_out, int out_size, void* d_ws, size_t ws_size,
                              hipStream_t stream) {
    const float* feature = (const float*)d_in[0];
    const float* W1 = (const float*)d_in[1];
    const float* b1 = (const float*)d_in[2];
    const float* W2 = (const float*)d_in[3];
    const float* b2 = (const float*)d_in[4];
    const float* Wm = (const float*)d_in[5];
    const float* bm = (const float*)d_in[6];
    const int* src = (const int*)d_in[7];
    const int* dst = (const int*)d_in[8];
    float* out = (float*)d_out;

    const int N = N_NODES, E = N_EDGES;

    char* p = (char*)d_ws;
    int* deg_src = (int*)p;    p += (size_t)N * 4;
    int* deg_dst = (int*)p;    p += (size_t)N * 4;
    float* out_norm = (float*)p; p += (size_t)N * 4;
    float* in_norm = (float*)p;  p += (size_t)N * 4;
    int* row_off = (int*)p;    p += (size_t)(N + 1) * 4;
    int* cursor = (int*)p;     p += (size_t)N * 4;
    int* bsums = (int*)p;      p += 512 * 4;
    int* csr_src = (int*)p;    p += (size_t)E * 4;
    float* X = (float*)p;      p += (size_t)N * 64 * 4;
    float* H = (float*)p;      p += (size_t)N * 64 * 4;

    hipMemsetAsync(deg_src, 0, (size_t)N * 4, stream);
    hipMemsetAsync(deg_dst, 0, (size_t)N * 4, stream);

    degree_kernel<<<(E + 255) / 256, 256, 0, stream>>>(src, dst, deg_src, deg_dst, E);
    norm_kernel<<<(N + 255) / 256, 256, 0, stream>>>(deg_src, deg_dst, out_norm, in_norm, N);

    int nScanBlocks = (N + 255) / 256;  // 391
    scan_block_kernel<<<nScanBlocks, 256, 0, stream>>>(deg_dst, row_off, bsums, N);
    scan_sums_kernel<<<1, 512, 0, stream>>>(bsums, nScanBlocks);
    scan_add_kernel<<<nScanBlocks, 256, 0, stream>>>(row_off, bsums, cursor, N, E);

    scatter_kernel<<<(E + 255) / 256, 256, 0, stream>>>(src, dst, cursor, csr_src, E);

    dim3 ggrid((N + 255) / 256, 2);
    // layer 1
    gemm_tpr_kernel<128><<<ggrid, 256, 0, stream>>>(feature, W1, out_norm, X, N);
    agg_kernel<false><<<(N + 3) / 4, 256, 0, stream>>>(X, row_off, csr_src, in_norm, b1,
                                                       nullptr, nullptr, H, N);
    // layer 2
    gemm_tpr_kernel<64><<<ggrid, 256, 0, stream>>>(H, W2, out_norm, X, N);
    // fused head
    agg_kernel<true><<<(N + 3) / 4, 256, 0, stream>>>(X, row_off, csr_src, in_norm, b2,
                                                      Wm, bm, out, N);
}

// Round 4
// 503.505 us; speedup vs baseline: 1.3920x; 1.1067x over previous
//
#include <hip/hip_runtime.h>

#define N_NODES 100000
#define N_EDGES 1600000
#define IN_F 128
#define H_F 64
#define NXCD 8
#define NODES_PER_XCD (N_NODES / NXCD)  // 12500 exactly

// ---------------- degree histogram, XCD-partitioned ----------------
// Block group x = blockIdx&7 (round-robins to XCD x) owns node range
// [x*12500, (x+1)*12500) for BOTH histograms: all its atomics stay in one
// XCD's L2 -> no cross-XCD dirty-line bounce. Each group streams the whole
// edge list; identical addresses across groups are L3-served.
__global__ __launch_bounds__(256) void degree_xcd_kernel(
        const int* __restrict__ src, const int* __restrict__ dst,
        int* __restrict__ deg_src, int* __restrict__ deg_dst, int E) {
    int xcd = blockIdx.x & (NXCD - 1);
    int group = blockIdx.x >> 3;
    int ngroups = gridDim.x >> 3;
    int lo = xcd * NODES_PER_XCD, hi = lo + NODES_PER_XCD;
    for (int e = group * blockDim.x + threadIdx.x; e < E; e += ngroups * blockDim.x) {
        int s = src[e];
        int d = dst[e];
        if (s >= lo && s < hi) atomicAdd(&deg_src[s], 1);
        if (d >= lo && d < hi) atomicAdd(&deg_dst[d], 1);
    }
}

__global__ void norm_kernel(const int* __restrict__ deg_src, const int* __restrict__ deg_dst,
                            float* __restrict__ out_norm, float* __restrict__ in_norm, int N) {
    int i = blockIdx.x * blockDim.x + threadIdx.x;
    if (i < N) {
        out_norm[i] = rsqrtf((float)max(deg_src[i], 1));
        in_norm[i]  = rsqrtf((float)max(deg_dst[i], 1));
    }
}

// ---------------- exclusive scan (3-phase) ----------------
__global__ void scan_block_kernel(const int* __restrict__ deg, int* __restrict__ out,
                                  int* __restrict__ bsums, int N) {
    __shared__ int temp[256];
    int tid = threadIdx.x;
    int i = blockIdx.x * 256 + tid;
    int v = (i < N) ? deg[i] : 0;
    temp[tid] = v;
    __syncthreads();
    for (int off = 1; off < 256; off <<= 1) {
        int t = (tid >= off) ? temp[tid - off] : 0;
        __syncthreads();
        temp[tid] += t;
        __syncthreads();
    }
    int excl = (tid > 0) ? temp[tid - 1] : 0;
    if (i < N) out[i] = excl;
    if (tid == 255) bsums[blockIdx.x] = temp[255];
}

__global__ void scan_sums_kernel(int* __restrict__ bsums, int B) {
    __shared__ int temp[512];
    int tid = threadIdx.x;
    int v = (tid < B) ? bsums[tid] : 0;
    temp[tid] = v;
    __syncthreads();
    for (int off = 1; off < 512; off <<= 1) {
        int t = (tid >= off) ? temp[tid - off] : 0;
        __syncthreads();
        temp[tid] += t;
        __syncthreads();
    }
    int excl = (tid > 0) ? temp[tid - 1] : 0;
    if (tid < B) bsums[tid] = excl;
}

__global__ void scan_add_kernel(int* __restrict__ row_off, const int* __restrict__ bsums,
                                int* __restrict__ cursor, int N, int E) {
    int i = blockIdx.x * 256 + threadIdx.x;
    if (i < N) {
        int r = row_off[i] + bsums[i >> 8];
        row_off[i] = r;
        cursor[i] = r;
    }
    if (i == 0) row_off[N] = E;
}

// ---------------- CSR scatter, XCD-partitioned ----------------
// Same ownership scheme: group x scatters only edges with dst in its range.
// Cursor slice (50 KB) and csr slice (~0.8 MB) stay resident in the owning
// XCD's L2 -> one writeback instead of ~16 bounces per line.
__global__ __launch_bounds__(256) void scatter_xcd_kernel(
        const int* __restrict__ src, const int* __restrict__ dst,
        int* __restrict__ cursor, int* __restrict__ csr_src, int E) {
    int xcd = blockIdx.x & (NXCD - 1);
    int group = blockIdx.x >> 3;
    int ngroups = gridDim.x >> 3;
    int lo = xcd * NODES_PER_XCD, hi = lo + NODES_PER_XCD;
    for (int e = group * blockDim.x + threadIdx.x; e < E; e += ngroups * blockDim.x) {
        int d = dst[e];
        if (d >= lo && d < hi) {
            int p = atomicAdd(&cursor[d], 1);
            csr_src[p] = src[e];
        }
    }
}

// ---------------- thread-per-row GEMM, 32-col half per blockIdx.y ----------------
template <int K>
__global__ __launch_bounds__(256, 4) void gemm_tpr_kernel(
        const float* __restrict__ in, const float* __restrict__ W,
        const float* __restrict__ scale, float* __restrict__ out, int N) {
    int r = blockIdx.x * blockDim.x + threadIdx.x;
    if (r >= N) return;
    const int h = blockIdx.y * 32;  // column half offset

    float acc[32];
#pragma unroll
    for (int j = 0; j < 32; j++) acc[j] = 0.f;

    const float* row = in + (size_t)r * K;
#pragma unroll 4
    for (int k = 0; k < K; k += 4) {
        float4 a = *reinterpret_cast<const float4*>(row + k);
        const float* w0 = W + (size_t)k * 64 + h;
#pragma unroll
        for (int j = 0; j < 32; j++) acc[j] = fmaf(a.x, w0[j], acc[j]);
#pragma unroll
        for (int j = 0; j < 32; j++) acc[j] = fmaf(a.y, w0[64 + j], acc[j]);
#pragma unroll
        for (int j = 0; j < 32; j++) acc[j] = fmaf(a.z, w0[128 + j], acc[j]);
#pragma unroll
        for (int j = 0; j < 32; j++) acc[j] = fmaf(a.w, w0[192 + j], acc[j]);
    }

    float s = scale[r];
    float4* o = reinterpret_cast<float4*>(out + (size_t)r * 64 + h);
#pragma unroll
    for (int j = 0; j < 32; j += 4) {
        float4 v;
        v.x = acc[j + 0] * s;
        v.y = acc[j + 1] * s;
        v.z = acc[j + 2] * s;
        v.w = acc[j + 3] * s;
        o[j >> 2] = v;
    }
}

// ---------------- CSR aggregation (one wave per node), optional fused 64->2 head ----------------
template <bool FUSE_HEAD>
__global__ __launch_bounds__(256) void agg_kernel(
        const float* __restrict__ X, const int* __restrict__ row_off,
        const int* __restrict__ csr_src, const float* __restrict__ in_norm,
        const float* __restrict__ bias, const float* __restrict__ Wm,
        const float* __restrict__ bm, float* __restrict__ out, int N) {
    int lane = threadIdx.x & 63;
    int wave = threadIdx.x >> 6;
    int v = blockIdx.x * (blockDim.x >> 6) + wave;
    if (v >= N) return;

    int start = row_off[v];
    int end = row_off[v + 1];
    float acc = 0.f;
    for (int base = start; base < end; base += 64) {
        int idx = base + lane;
        int s_e = (idx < end) ? csr_src[idx] : 0;
        int cnt = min(64, end - base);
        for (int t = 0; t < cnt; t++) {
            int s = __shfl(s_e, t);
            acc += X[(size_t)s * 64 + lane];
        }
    }
    float h = fmaf(acc, in_norm[v], bias[lane]);
    h = fmaxf(h, 0.f);

    if (!FUSE_HEAD) {
        out[(size_t)v * 64 + lane] = h;
    } else {
        float p0 = h * Wm[lane * 2 + 0];
        float p1 = h * Wm[lane * 2 + 1];
#pragma unroll
        for (int off = 32; off > 0; off >>= 1) {
            p0 += __shfl_xor(p0, off);
            p1 += __shfl_xor(p1, off);
        }
        if (lane == 0) {
            out[(size_t)v * 2 + 0] = p0 + bm[0];
            out[(size_t)v * 2 + 1] = p1 + bm[1];
        }
    }
}

extern "C" void kernel_launch(void* const* d_in, const int* in_sizes, int n_in,
                              void* d_out, int out_size, void* d_ws, size_t ws_size,
                              hipStream_t stream) {
    const float* feature = (const float*)d_in[0];
    const float* W1 = (const float*)d_in[1];
    const float* b1 = (const float*)d_in[2];
    const float* W2 = (const float*)d_in[3];
    const float* b2 = (const float*)d_in[4];
    const float* Wm = (const float*)d_in[5];
    const float* bm = (const float*)d_in[6];
    const int* src = (const int*)d_in[7];
    const int* dst = (const int*)d_in[8];
    float* out = (float*)d_out;

    const int N = N_NODES, E = N_EDGES;

    char* p = (char*)d_ws;
    int* deg_src = (int*)p;    p += (size_t)N * 4;
    int* deg_dst = (int*)p;    p += (size_t)N * 4;
    float* out_norm = (float*)p; p += (size_t)N * 4;
    float* in_norm = (float*)p;  p += (size_t)N * 4;
    int* row_off = (int*)p;    p += (size_t)(N + 1) * 4;
    int* cursor = (int*)p;     p += (size_t)N * 4;
    int* bsums = (int*)p;      p += 512 * 4;
    int* csr_src = (int*)p;    p += (size_t)E * 4;
    float* X = (float*)p;      p += (size_t)N * 64 * 4;
    float* H = (float*)p;      p += (size_t)N * 64 * 4;

    hipMemsetAsync(deg_src, 0, (size_t)N * 4, stream);
    hipMemsetAsync(deg_dst, 0, (size_t)N * 4, stream);

    degree_xcd_kernel<<<1024, 256, 0, stream>>>(src, dst, deg_src, deg_dst, E);
    norm_kernel<<<(N + 255) / 256, 256, 0, stream>>>(deg_src, deg_dst, out_norm, in_norm, N);

    int nScanBlocks = (N + 255) / 256;  // 391
    scan_block_kernel<<<nScanBlocks, 256, 0, stream>>>(deg_dst, row_off, bsums, N);
    scan_sums_kernel<<<1, 512, 0, stream>>>(bsums, nScanBlocks);
    scan_add_kernel<<<nScanBlocks, 256, 0, stream>>>(row_off, bsums, cursor, N, E);

    scatter_xcd_kernel<<<1024, 256, 0, stream>>>(src, dst, cursor, csr_src, E);

    dim3 ggrid((N + 255) / 256, 2);
    // layer 1
    gemm_tpr_kernel<128><<<ggrid, 256, 0, stream>>>(feature, W1, out_norm, X, N);
    agg_kernel<false><<<(N + 3) / 4, 256, 0, stream>>>(X, row_off, csr_src, in_norm, b1,
                                                       nullptr, nullptr, H, N);
    // layer 2
    gemm_tpr_kernel<64><<<ggrid, 256, 0, stream>>>(H, W2, out_norm, X, N);
    // fused head
    agg_kernel<true><<<(N + 3) / 4, 256, 0, stream>>>(X, row_off, csr_src, in_norm, b2,
                                                      Wm, bm, out, N);
}